// Round 15
// baseline (485.031 us; speedup 1.0000x reference)
//
#include <hip/hip_runtime.h>

typedef unsigned long long u64;

#define N1c 4096
#define N2c 49152
#define Dc 512
#define SPLITc 24576
#define NSPLITc 2
#define CAPc 65536
#define WPSc (SPLITc / 64)   /* 384 mask words per row per split */
#define SIM_Tc 0.2f
#define AMB_Tc 0.17f
#define DELTAc 0.01f         /* bf16-vs-f32 safety band half-width (bound ~0.008) */
#define CANDMAX (1 << 20)

typedef __bf16 bf16x8 __attribute__((ext_vector_type(8)));
typedef float f32x4 __attribute__((ext_vector_type(4)));

static __device__ __forceinline__ unsigned short f2bf(float x) {
  unsigned u = __float_as_uint(x);
  unsigned r = (u + 0x7fffu + ((u >> 16) & 1u)) >> 16;   // RNE
  return (unsigned short)r;
}

// ---------------------------------------------------------------- fill out=-1
__global__ void sim_fill_out_k(int* __restrict__ out, int n) {
  int i = blockIdx.x * blockDim.x + threadIdx.x;
  if (i < n) out[i] = -1;
}

__global__ void sim_zero_k(int* __restrict__ p) { if (threadIdx.x == 0) *p = 0; }

// ---------------------------------------------------------------- norms (+ bf16 queries + split-0 db)
__global__ void sim_norm_k(const float* __restrict__ f1, const float* __restrict__ f2,
                           float* __restrict__ invn, unsigned short* __restrict__ f1nb,
                           unsigned short* __restrict__ f2nb) {
  int wid = threadIdx.x >> 6, lane = threadIdx.x & 63;
  int row = blockIdx.x * 4 + wid;
  if (row >= N1c + N2c) return;
  const float* src = (row < N1c) ? (f1 + (size_t)row * Dc)
                                 : (f2 + (size_t)(row - N1c) * Dc);
  const float4* p = (const float4*)src;
  float4 v0 = p[lane];
  float4 v1 = p[lane + 64];
  float ss = v0.x*v0.x + v0.y*v0.y + v0.z*v0.z + v0.w*v0.w
           + v1.x*v1.x + v1.y*v1.y + v1.z*v1.z + v1.w*v1.w;
  #pragma unroll
  for (int d = 1; d < 64; d <<= 1) ss += __shfl_xor(ss, d);
  float inv = 1.0f / fmaxf(sqrtf(ss), 1e-12f);
  if (lane == 0) invn[row] = inv;
  unsigned short* dst = 0;
  if (row < N1c) dst = f1nb + (size_t)row * Dc;
  else if (row < N1c + SPLITc) dst = f2nb + (size_t)(row - N1c) * Dc;
  if (dst) {
    ushort4 o0, o1;
    o0.x = f2bf(v0.x*inv); o0.y = f2bf(v0.y*inv); o0.z = f2bf(v0.z*inv); o0.w = f2bf(v0.w*inv);
    o1.x = f2bf(v1.x*inv); o1.y = f2bf(v1.y*inv); o1.z = f2bf(v1.z*inv); o1.w = f2bf(v1.w*inv);
    ushort4* q = (ushort4*)dst;
    q[lane] = o0; q[lane + 64] = o1;
  }
}

// ---------------------------------------------------------------- per-split db -> normalized bf16 (split 1 only)
__global__ void sim_conv2_k(const float* __restrict__ f2, const float* __restrict__ invn,
                            unsigned short* __restrict__ f2nb, int s) {
  int wid = threadIdx.x >> 6, lane = threadIdx.x & 63;
  int rloc = blockIdx.x * 4 + wid;
  if (rloc >= SPLITc) return;
  int grow = s * SPLITc + rloc;
  float inv = invn[N1c + grow];
  const float4* p = (const float4*)(f2 + (size_t)grow * Dc);
  float4 v0 = p[lane];
  float4 v1 = p[lane + 64];
  ushort4 o0, o1;
  o0.x = f2bf(v0.x*inv); o0.y = f2bf(v0.y*inv); o0.z = f2bf(v0.z*inv); o0.w = f2bf(v0.w*inv);
  o1.x = f2bf(v1.x*inv); o1.y = f2bf(v1.y*inv); o1.z = f2bf(v1.z*inv); o1.w = f2bf(v1.w*inv);
  ushort4* q = (ushort4*)(f2nb + (size_t)rloc * Dc);
  q[lane] = o0; q[lane + 64] = o1;
}

// ---------------------------------------------------------------- bf16 MFMA GEMM + classify
// FAITHFUL 8-phase port (m201 template): 256x256 tile, BK=64, 8 waves (2Mx4N),
// wave output 128x64. K=512 -> 8 K-tiles x 4 quadrant-phases = 32 phases.
// Per phase: {ds_read subtile || stage 1 half-tile (2 gload_lds)} -> barrier
// -> MFMA x16 (setprio-wrapped) -> barrier. Counted vmcnt(2) ONLY at tile
// boundaries (next tile's part-0 stays in flight). Stage always writes the
// buffer NOT being read this tile; sched_barrier(0) fences stop compiler
// motion across the correctness-critical barriers. XOR swizzle + T1 verbatim.
__global__ __launch_bounds__(512, 2) void sim_mfma_k(
    const unsigned short* __restrict__ Abf, const unsigned short* __restrict__ Bbf,
    const int* __restrict__ labels, const int* __restrict__ indexes,
    const int* __restrict__ labels_db, const int* __restrict__ indexes_db,
    u64* __restrict__ msim, u64* __restrict__ mamb,
    unsigned* __restrict__ cands, int* __restrict__ ccount, int s)
{
  __shared__ __align__(16) unsigned short As[2][256 * 64];   // 2 x 32 KB
  __shared__ __align__(16) unsigned short Bs[2][256 * 64];   // 2 x 32 KB
  __shared__ u64 wS[256][4];                                 // 8 KB
  __shared__ u64 wA[256][4];                                 // 8 KB
  __shared__ int meta[1024];                                 // 4 KB

  const int tid  = threadIdx.x;
  const int lane = tid & 63;
  const int wid  = tid >> 6;          // 0..7
  const int wm   = wid >> 2;          // 0..1 : row half (128 rows)
  const int wn   = wid & 3;           // 0..3 : col quarter (64 cols)
  const int rbase = blockIdx.y * 256;
  // T1 bijective XCD chunk swizzle (96 = 8 * 12)
  const int bx   = blockIdx.x;
  const int cbase = ((bx & 7) * 12 + (bx >> 3)) * 256;   // column within split

  // meta preload (coalesced; latency hidden under prologue staging)
  {
    int gcb = s * SPLITc + cbase;
    meta[tid]       = (tid < 256) ? labels[rbase + tid]   : indexes[rbase + tid - 256];
    meta[512 + tid] = (tid < 256) ? labels_db[gcb + tid]  : indexes_db[gcb + tid - 256];
  }
  // zero mask staging (only touched again after the K-loop)
  #pragma unroll
  for (int i = 0; i < 2; ++i) {
    int w = tid * 2 + i;              // 0..1023
    wS[w >> 2][w & 3] = 0;
    wA[w >> 2][w & 3] = 0;
  }

  f32x4 acc[8][4];
  #pragma unroll
  for (int i = 0; i < 8; ++i)
    #pragma unroll
    for (int j = 0; j < 4; ++j) acc[i][j] = (f32x4){0.f, 0.f, 0.f, 0.f};

  // stage half-tile `part` of K-tile `st`: part 0=A-low,1=A-high,2=B-low,3=B-high
  // 2 gload_lds/wave; linear LDS dest (wave-uniform base + lane*16B);
  // inverse-swizzled global source (slot ^= row&7) matching the ds_read XOR.
#define STAGE_PART(st, part) do {                                                \
    if ((st) < 8) {                                                              \
      const int pb_ = (st) & 1; const int kb_ = (st) * 64;                       \
      const int h_ = (part) & 1; const bool isB_ = (part) >= 2;                  \
      _Pragma("unroll")                                                          \
      for (int l_ = 0; l_ < 2; ++l_) {                                           \
        int i_  = h_ * 2 + l_;                                                   \
        int row_ = i_ * 64 + wid * 8 + (lane >> 3);                              \
        int ls_  = (lane & 7) ^ (row_ & 7);                                      \
        const unsigned short* g_ = (isB_ ? Bbf + (size_t)(cbase + row_) * Dc     \
                                         : Abf + (size_t)(rbase + row_) * Dc)    \
                                   + kb_ + ls_ * 8;                              \
        __builtin_amdgcn_global_load_lds(                                        \
            (const __attribute__((address_space(1))) void*)g_,                   \
            (__attribute__((address_space(3))) void*)                            \
                (&(isB_ ? Bs : As)[pb_][i_ * 4096 + wid * 512]), 16, 0, 0);      \
      }                                                                          \
    } } while (0)

  // prologue: K-tile 0 fully staged (8 loads/wave in flight)
  STAGE_PART(0, 0); STAGE_PART(0, 1); STAGE_PART(0, 2); STAGE_PART(0, 3);

  bf16x8 bq[2][4];   // b fragments cached across the tile's 4 phases

  #pragma unroll
  for (int t = 0; t < 8; ++t) {
    const int pb = t & 1;
    #pragma unroll
    for (int q = 0; q < 4; ++q) {
      const int kk = q & 1, mh = q >> 1;
      if (q == 0) {
        STAGE_PART(t + 1, 0);
        if (t < 7) asm volatile("s_waitcnt vmcnt(2)" ::: "memory");
        else       asm volatile("s_waitcnt vmcnt(0)" ::: "memory");
        __builtin_amdgcn_sched_barrier(0);
        __builtin_amdgcn_s_barrier();     // buf pb now valid for ALL waves
        __builtin_amdgcn_sched_barrier(0);
      } else {
        STAGE_PART(t + 1, q);             // writes buf !pb (not read this tile)
      }
      // ds_read this phase's fragments (compiler inserts precise lgkmcnt)
      if (q < 2) {
        #pragma unroll
        for (int ni = 0; ni < 4; ++ni) {
          int r  = wn * 64 + ni * 16 + (lane & 15);
          int ps = (kk * 4 + (lane >> 4)) ^ (r & 7);
          bq[kk][ni] = *(const bf16x8*)(const void*)(&Bs[pb][r * 64 + ps * 8]);
        }
      }
      bf16x8 a_[4];
      #pragma unroll
      for (int mi = 0; mi < 4; ++mi) {
        int r  = wm * 128 + (mh * 4 + mi) * 16 + (lane & 15);
        int ps = (kk * 4 + (lane >> 4)) ^ (r & 7);
        a_[mi] = *(const bf16x8*)(const void*)(&As[pb][r * 64 + ps * 8]);
      }
      if (q != 0) __builtin_amdgcn_s_barrier();   // phase alignment
      __builtin_amdgcn_s_setprio(1);
      #pragma unroll
      for (int mi = 0; mi < 4; ++mi)
        #pragma unroll
        for (int ni = 0; ni < 4; ++ni)
          acc[mh * 4 + mi][ni] = __builtin_amdgcn_mfma_f32_16x16x32_bf16(
              a_[mi], bq[kk][ni], acc[mh * 4 + mi][ni], 0, 0, 0);
      __builtin_amdgcn_s_setprio(0);
      __builtin_amdgcn_s_barrier();       // phase end
      __builtin_amdgcn_sched_barrier(0);  // nothing hoists above phase end
    }
  }
#undef STAGE_PART

  __syncthreads();

  // ---- classify into bit masks (C layout: col=lane&15, row=(lane>>4)*4+reg) ----
  int lab2[4], idx2[4], cloc[4];
  #pragma unroll
  for (int ni = 0; ni < 4; ++ni) {
    int cl = wn * 64 + ni * 16 + (lane & 15);   // 0..255 within tile
    cloc[ni] = cbase + cl;
    lab2[ni] = meta[512 + cl];
    idx2[ni] = meta[768 + cl];
  }

  #pragma unroll
  for (int mi = 0; mi < 8; ++mi) {
    #pragma unroll
    for (int rr = 0; rr < 4; ++rr) {
      int row256 = wm * 128 + mi * 16 + (lane >> 4) * 4 + rr;
      int gr = rbase + row256;
      int lab1 = meta[row256], idx1 = meta[256 + row256];
      u64 sb = 0, ab = 0;
      #pragma unroll
      for (int ni = 0; ni < 4; ++ni) {
        float v = acc[mi][ni][rr];
        if (idx1 < idx2[ni] && lab1 != lab2[ni]) {
          if (v > SIM_Tc + DELTAc) {
            sb |= 1ull << (ni * 16 + (lane & 15));
          } else if (v > AMB_Tc - DELTAc) {
            if (v < SIM_Tc - DELTAc && v > AMB_Tc + DELTAc) {
              ab |= 1ull << (ni * 16 + (lane & 15));
            } else {   // within ±DELTA of a threshold: exact f32 recheck later
              int ci = atomicAdd(ccount, 1);
              if (ci < CANDMAX)
                cands[ci] = ((unsigned)gr << 15) | (unsigned)cloc[ni];
            }
          }
        }
      }
      if (sb) atomicOr(&wS[row256][wn], sb);
      if (ab) atomicOr(&wA[row256][wn], ab);
    }
  }
  __syncthreads();
  #pragma unroll
  for (int i = 0; i < 2; ++i) {
    int w = tid * 2 + i;              // 0..1023
    int row = w >> 2, jh = w & 3;
    size_t widx = (size_t)(rbase + row) * WPSc + (cbase >> 6) + jh;
    msim[widx] = wS[row][jh];
    mamb[widx] = wA[row][jh];
  }
}

// ---------------------------------------------------------------- exact f32 recheck of band pairs
__global__ void sim_recheck_k(const float* __restrict__ f1, const float* __restrict__ f2,
                              const float* __restrict__ invn,
                              const unsigned* __restrict__ cands, const int* __restrict__ ccount,
                              u64* __restrict__ msim, u64* __restrict__ mamb, int s) {
  int lane = threadIdx.x & 63;
  int gw = (blockIdx.x * blockDim.x + threadIdx.x) >> 6;
  int nw = (gridDim.x * blockDim.x) >> 6;
  int n = *ccount; if (n > CANDMAX) n = CANDMAX;
  for (int i = gw; i < n; i += nw) {
    unsigned pk = cands[i];
    int r = (int)(pk >> 15), c = (int)(pk & 0x7fffu);
    const float4* pa = (const float4*)(f1 + (size_t)r * Dc);
    const float4* pb = (const float4*)(f2 + ((size_t)s * SPLITc + c) * Dc);
    float4 a0 = pa[lane], a1 = pa[lane + 64];
    float4 b0 = pb[lane], b1 = pb[lane + 64];
    float d = a0.x*b0.x + a0.y*b0.y + a0.z*b0.z + a0.w*b0.w
            + a1.x*b1.x + a1.y*b1.y + a1.z*b1.z + a1.w*b1.w;
    #pragma unroll
    for (int t = 1; t < 64; t <<= 1) d += __shfl_xor(d, t);
    if (lane == 0) {
      float v = d * invn[r] * invn[N1c + s * SPLITc + c];
      if (v > SIM_Tc)
        atomicOr(&msim[(size_t)r * WPSc + (c >> 6)], 1ull << (c & 63));
      else if (v > AMB_Tc)
        atomicOr(&mamb[(size_t)r * WPSc + (c >> 6)], 1ull << (c & 63));
    }
  }
}

// ---------------------------------------------------------------- per-row counts
__global__ void sim_rowcount_k(const u64* __restrict__ msim, const u64* __restrict__ mamb,
                               int* __restrict__ rowcnt) {
  int row = blockIdx.x;
  int wid = threadIdx.x >> 6, lane = threadIdx.x & 63;
  const u64* m = wid ? mamb : msim;
  int ssum = 0;
  #pragma unroll
  for (int it = 0; it < WPSc / 64; ++it)
    ssum += __popcll(m[(size_t)row * WPSc + it * 64 + lane]);
  #pragma unroll
  for (int d = 32; d; d >>= 1) ssum += __shfl_down(ssum, d);
  if (lane == 0) rowcnt[wid * N1c + row] = ssum;
}

// ---------------------------------------------------------------- exclusive scan over 4096 rows
__global__ void sim_scan_k(const int* __restrict__ rowcnt, int* __restrict__ rowoff) {
  int cat = blockIdx.x;
  int tid = threadIdx.x;                  // 256 threads x 16 rows
  int v[16]; int ssum = 0;
  #pragma unroll
  for (int i = 0; i < 16; ++i) { v[i] = rowcnt[cat * N1c + tid * 16 + i]; ssum += v[i]; }
  int lane = tid & 63, wid = tid >> 6;
  int incl = ssum;
  #pragma unroll
  for (int d = 1; d < 64; d <<= 1) { int t = __shfl_up(incl, d); if (lane >= d) incl += t; }
  __shared__ int wsum[4];
  if (lane == 63) wsum[wid] = incl;
  __syncthreads();
  int woff = 0;
  for (int w = 0; w < wid; ++w) woff += wsum[w];
  int run = woff + incl - ssum;
  #pragma unroll
  for (int i = 0; i < 16; ++i) { rowoff[cat * N1c + tid * 16 + i] = run; run += v[i]; }
}

// ---------------------------------------------------------------- ordered scatter
__global__ void sim_scatter_k(const u64* __restrict__ msim, const u64* __restrict__ mamb,
                              const int* __restrict__ rowoff,
                              const int* __restrict__ labels, const int* __restrict__ counts,
                              const int* __restrict__ labels_db, const int* __restrict__ counts_db,
                              int* __restrict__ out, int s) {
  int row = blockIdx.x;
  int cat = blockIdx.y;
  int lane = threadIdx.x;
  const u64* m = cat ? mamb : msim;
  int* o = out + (cat ? (NSPLITc * CAPc * 2 + s * CAPc * 2) : (s * CAPc * 2));
  int run = rowoff[cat * N1c + row];
  int lab1 = labels[row];
  int cnt1 = counts[row];
  for (int it = 0; it < WPSc / 64; ++it) {
    int w = it * 64 + lane;
    u64 x = m[(size_t)row * WPSc + w];
    int pc = __popcll(x);
    int incl = pc;
    #pragma unroll
    for (int d = 1; d < 64; d <<= 1) { int t = __shfl_up(incl, d); if (lane >= d) incl += t; }
    int pos = run + incl - pc;
    int tot = __shfl(incl, 63);
    while (x) {
      int b = __builtin_ctzll(x);
      x &= x - 1;
      if (pos < CAPc) {
        int gc = s * SPLITc + w * 64 + b;
        int l2v = labels_db[gc];
        if (cat == 0) {
          o[2 * pos]     = lab1;
          o[2 * pos + 1] = l2v;
        } else {
          bool sw = cnt1 > counts_db[gc];
          o[2 * pos]     = sw ? l2v : lab1;
          o[2 * pos + 1] = sw ? lab1 : l2v;
        }
      }
      ++pos;
    }
    run += tot;
  }
}

// ---------------------------------------------------------------- launcher
extern "C" void kernel_launch(void* const* d_in, const int* in_sizes, int n_in,
                              void* d_out, int out_size, void* d_ws, size_t ws_size,
                              hipStream_t stream) {
  const float* features    = (const float*)d_in[0];
  const int*   labels      = (const int*)  d_in[1];
  const int*   counts      = (const int*)  d_in[2];
  const int*   indexes     = (const int*)  d_in[3];
  const float* features_db = (const float*)d_in[4];
  const int*   labels_db   = (const int*)  d_in[5];
  const int*   counts_db   = (const int*)  d_in[6];
  const int*   indexes_db  = (const int*)  d_in[7];
  int* out = (int*)d_out;

  // workspace layout (~57.5 MB)
  u64*   msim   = (u64*)d_ws;                           // 12.58 MB
  u64*   mamb   = msim + (size_t)N1c * WPSc;            // 12.58 MB
  float* invn   = (float*)(mamb + (size_t)N1c * WPSc);  // (N1+N2) f32
  int*   rowcnt = (int*)(invn + (N1c + N2c));           // [2][N1]
  int*   rowoff = rowcnt + 2 * N1c;                     // [2][N1]
  int*   ccount = rowoff + 2 * N1c;                     // 1 (+pad)
  unsigned* cands = (unsigned*)(ccount + 4);            // 4 MB
  unsigned short* f1nb = (unsigned short*)(cands + CANDMAX);  // 4 MB
  unsigned short* f2nb = f1nb + (size_t)N1c * Dc;       // 24 MB (per split, reused)

  sim_fill_out_k<<<(out_size + 255) / 256, 256, 0, stream>>>(out, out_size);
  sim_norm_k<<<(N1c + N2c + 3) / 4, 256, 0, stream>>>(features, features_db, invn, f1nb, f2nb);

  for (int s = 0; s < NSPLITc; ++s) {
    if (s) sim_conv2_k<<<SPLITc / 4, 256, 0, stream>>>(features_db, invn, f2nb, s);
    sim_zero_k<<<1, 64, 0, stream>>>(ccount);
    sim_mfma_k<<<dim3(SPLITc / 256, N1c / 256), 512, 0, stream>>>(
        f1nb, f2nb, labels, indexes, labels_db, indexes_db,
        msim, mamb, cands, ccount, s);
    sim_recheck_k<<<512, 256, 0, stream>>>(features, features_db, invn,
                                           cands, ccount, msim, mamb, s);
    sim_rowcount_k<<<N1c, 128, 0, stream>>>(msim, mamb, rowcnt);
    sim_scan_k<<<2, 256, 0, stream>>>(rowcnt, rowoff);
    sim_scatter_k<<<dim3(N1c, 2), 64, 0, stream>>>(
        msim, mamb, rowoff, labels, counts, labels_db, counts_db, out, s);
  }
}

// Round 16
// 360.394 us; speedup vs baseline: 1.3458x; 1.3458x over previous
//
#include <hip/hip_runtime.h>

typedef unsigned long long u64;

#define N1c 4096
#define N2c 49152
#define Dc 512
#define SPLITc 24576
#define NSPLITc 2
#define CAPc 65536
#define WPSc (SPLITc / 64)   /* 384 mask words per row per split */
#define SIM_Tc 0.2f
#define AMB_Tc 0.17f
#define DELTAc 0.01f         /* bf16-vs-f32 safety band half-width (bound ~0.008) */
#define CANDMAX (1 << 20)

typedef __bf16 bf16x8 __attribute__((ext_vector_type(8)));
typedef float f32x4 __attribute__((ext_vector_type(4)));

static __device__ __forceinline__ unsigned short f2bf(float x) {
  unsigned u = __float_as_uint(x);
  unsigned r = (u + 0x7fffu + ((u >> 16) & 1u)) >> 16;   // RNE
  return (unsigned short)r;
}

// ---------------------------------------------------------------- fill out=-1 (+ zero both split counters)
__global__ void sim_fill_out_k(int* __restrict__ out, int n, int* __restrict__ ccount) {
  int i = blockIdx.x * blockDim.x + threadIdx.x;
  if (i < n) out[i] = -1;
  if (i < NSPLITc) ccount[i] = 0;
}

// ---------------------------------------------------------------- norms (+ bf16 queries + split-0 db)
__global__ void sim_norm_k(const float* __restrict__ f1, const float* __restrict__ f2,
                           float* __restrict__ invn, unsigned short* __restrict__ f1nb,
                           unsigned short* __restrict__ f2nb) {
  int wid = threadIdx.x >> 6, lane = threadIdx.x & 63;
  int row = blockIdx.x * 4 + wid;
  if (row >= N1c + N2c) return;
  const float* src = (row < N1c) ? (f1 + (size_t)row * Dc)
                                 : (f2 + (size_t)(row - N1c) * Dc);
  const float4* p = (const float4*)src;
  float4 v0 = p[lane];
  float4 v1 = p[lane + 64];
  float ss = v0.x*v0.x + v0.y*v0.y + v0.z*v0.z + v0.w*v0.w
           + v1.x*v1.x + v1.y*v1.y + v1.z*v1.z + v1.w*v1.w;
  #pragma unroll
  for (int d = 1; d < 64; d <<= 1) ss += __shfl_xor(ss, d);
  float inv = 1.0f / fmaxf(sqrtf(ss), 1e-12f);
  if (lane == 0) invn[row] = inv;
  unsigned short* dst = 0;
  if (row < N1c) dst = f1nb + (size_t)row * Dc;
  else if (row < N1c + SPLITc) dst = f2nb + (size_t)(row - N1c) * Dc;
  if (dst) {
    ushort4 o0, o1;
    o0.x = f2bf(v0.x*inv); o0.y = f2bf(v0.y*inv); o0.z = f2bf(v0.z*inv); o0.w = f2bf(v0.w*inv);
    o1.x = f2bf(v1.x*inv); o1.y = f2bf(v1.y*inv); o1.z = f2bf(v1.z*inv); o1.w = f2bf(v1.w*inv);
    ushort4* q = (ushort4*)dst;
    q[lane] = o0; q[lane + 64] = o1;
  }
}

// ---------------------------------------------------------------- per-split db -> normalized bf16 (split 1 only)
__global__ void sim_conv2_k(const float* __restrict__ f2, const float* __restrict__ invn,
                            unsigned short* __restrict__ f2nb, int s) {
  int wid = threadIdx.x >> 6, lane = threadIdx.x & 63;
  int rloc = blockIdx.x * 4 + wid;
  if (rloc >= SPLITc) return;
  int grow = s * SPLITc + rloc;
  float inv = invn[N1c + grow];
  const float4* p = (const float4*)(f2 + (size_t)grow * Dc);
  float4 v0 = p[lane];
  float4 v1 = p[lane + 64];
  ushort4 o0, o1;
  o0.x = f2bf(v0.x*inv); o0.y = f2bf(v0.y*inv); o0.z = f2bf(v0.z*inv); o0.w = f2bf(v0.w*inv);
  o1.x = f2bf(v1.x*inv); o1.y = f2bf(v1.y*inv); o1.z = f2bf(v1.z*inv); o1.w = f2bf(v1.w*inv);
  ushort4* q = (ushort4*)(f2nb + (size_t)rloc * Dc);
  q[lane] = o0; q[lane + 64] = o1;
}

// ---------------------------------------------------------------- bf16 MFMA GEMM + classify
// R14 VERBATIM (proven best: 160 us/dispatch, MfmaUtil 28%, 364 us total):
// 128x128 tile, BK=64, 4 waves (2x2), serial 2-barrier K-steps, T1 XCD
// column-chunk swizzle, coalesced meta-LDS preload for the classify epilogue.
// Structural plateau analysis: at K=512 (8 K-steps/block) the per-K-step
// stage+drain latency can only be hidden by cross-block TLP; 16 waves/CU is
// the VGPR wall (128 regs/wave); every LDS-heavier pipeline variant (R7, R8,
// R10, R11, R13, R15) halved blocks/CU and regressed to 17-19% MfmaUtil.
__global__ __launch_bounds__(256, 2) void sim_mfma_k(
    const unsigned short* __restrict__ Abf, const unsigned short* __restrict__ Bbf,
    const int* __restrict__ labels, const int* __restrict__ indexes,
    const int* __restrict__ labels_db, const int* __restrict__ indexes_db,
    u64* __restrict__ msim, u64* __restrict__ mamb,
    unsigned* __restrict__ cands, int* __restrict__ ccount, int s)
{
  __shared__ unsigned short As[128 * 64];   // 16 KB, rows of 128B, slot-swizzled
  __shared__ unsigned short Bs[128 * 64];   // 16 KB
  __shared__ u64 wS[128][2];                // 2 KB
  __shared__ u64 wA[128][2];                // 2 KB
  __shared__ int meta[512];                 // 2 KB: [0:128) row lab, [128:256) row idx,
                                            //       [256:384) col lab, [384:512) col idx

  const int tid  = threadIdx.x;
  const int lane = tid & 63;
  const int wid  = tid >> 6;
  const int wm   = wid >> 1, wn = wid & 1;
  const int rbase = blockIdx.y * 128;
  // T1 bijective XCD chunk swizzle (192 = 8 * 24): each XCD owns 24 contiguous
  // column tiles -> 3.07 MB B working set, L2-resident across row sweeps.
  const int bx   = blockIdx.x;
  const int cbase = ((bx & 7) * 24 + (bx >> 3)) * 128;   // column within split

  // coalesced metadata preload (issued before K-loop; visible by epilogue's syncs)
  {
    int r0 = tid & 127;
    bool hi = tid >= 128;
    int gcb = s * SPLITc + cbase;
    meta[tid]       = hi ? indexes[rbase + r0]    : labels[rbase + r0];
    meta[256 + tid] = hi ? indexes_db[gcb + r0]   : labels_db[gcb + r0];
  }

  f32x4 acc[4][4];
  #pragma unroll
  for (int i = 0; i < 4; ++i)
    #pragma unroll
    for (int j = 0; j < 4; ++j) acc[i][j] = (f32x4){0.f, 0.f, 0.f, 0.f};

  for (int kb = 0; kb < Dc; kb += 64) {
    __syncthreads();
    #pragma unroll
    for (int c4 = 0; c4 < 4; ++c4) {
      int c   = wid * 4 + c4;                 // chunk 0..15 (8 rows each)
      int row = c * 8 + (lane >> 3);
      int ls  = (lane & 7) ^ (row & 7);       // logical k-slot for this phys slot
      const unsigned short* ga = Abf + (size_t)(rbase + row) * Dc + kb + ls * 8;
      const unsigned short* gb = Bbf + (size_t)(cbase + row) * Dc + kb + ls * 8;
      __builtin_amdgcn_global_load_lds((const __attribute__((address_space(1))) void*)ga,
          (__attribute__((address_space(3))) void*)(As + c * 512), 16, 0, 0);
      __builtin_amdgcn_global_load_lds((const __attribute__((address_space(1))) void*)gb,
          (__attribute__((address_space(3))) void*)(Bs + c * 512), 16, 0, 0);
    }
    __syncthreads();   // compiler drains vmcnt before barrier
    #pragma unroll
    for (int kk = 0; kk < 2; ++kk) {
      bf16x8 a[4], b[4];
      #pragma unroll
      for (int mi = 0; mi < 4; ++mi) {
        int r  = wm * 64 + mi * 16 + (lane & 15);
        int ps = (kk * 4 + (lane >> 4)) ^ (r & 7);
        a[mi] = *(const bf16x8*)(const void*)(As + r * 64 + ps * 8);
      }
      #pragma unroll
      for (int ni = 0; ni < 4; ++ni) {
        int r  = wn * 64 + ni * 16 + (lane & 15);
        int ps = (kk * 4 + (lane >> 4)) ^ (r & 7);
        b[ni] = *(const bf16x8*)(const void*)(Bs + r * 64 + ps * 8);
      }
      #pragma unroll
      for (int mi = 0; mi < 4; ++mi)
        #pragma unroll
        for (int ni = 0; ni < 4; ++ni)
          acc[mi][ni] = __builtin_amdgcn_mfma_f32_16x16x32_bf16(a[mi], b[ni], acc[mi][ni], 0, 0, 0);
    }
  }

  // ---- classify into bit masks (C layout: col=lane&15, row=(lane>>4)*4+reg) ----
  wS[tid >> 1][tid & 1] = 0;
  wA[tid >> 1][tid & 1] = 0;
  __syncthreads();

  int lab2[4], idx2[4], cloc[4];
  #pragma unroll
  for (int ni = 0; ni < 4; ++ni) {
    int cl = wn * 64 + ni * 16 + (lane & 15);   // 0..127 within tile
    cloc[ni] = cbase + cl;
    lab2[ni] = meta[256 + cl];
    idx2[ni] = meta[384 + cl];
  }

  #pragma unroll
  for (int mi = 0; mi < 4; ++mi) {
    #pragma unroll
    for (int r = 0; r < 4; ++r) {
      int row128 = wm * 64 + mi * 16 + (lane >> 4) * 4 + r;
      int gr = rbase + row128;
      int lab1 = meta[row128], idx1 = meta[128 + row128];
      u64 sb = 0, ab = 0;
      #pragma unroll
      for (int ni = 0; ni < 4; ++ni) {
        float v = acc[mi][ni][r];
        if (idx1 < idx2[ni] && lab1 != lab2[ni]) {
          if (v > SIM_Tc + DELTAc) {
            sb |= 1ull << (ni * 16 + (lane & 15));
          } else if (v > AMB_Tc - DELTAc) {
            if (v < SIM_Tc - DELTAc && v > AMB_Tc + DELTAc) {
              ab |= 1ull << (ni * 16 + (lane & 15));
            } else {   // within ±DELTA of a threshold: exact f32 recheck later
              int ci = atomicAdd(ccount, 1);
              if (ci < CANDMAX)
                cands[ci] = ((unsigned)gr << 15) | (unsigned)cloc[ni];
            }
          }
        }
      }
      if (sb) atomicOr(&wS[row128][wn], sb);
      if (ab) atomicOr(&wA[row128][wn], ab);
    }
  }
  __syncthreads();
  {
    int row128 = tid >> 1, jh = tid & 1;
    size_t w = (size_t)(rbase + row128) * WPSc + (cbase >> 6) + jh;
    msim[w] = wS[row128][jh];
    mamb[w] = wA[row128][jh];
  }
}

// ---------------------------------------------------------------- exact f32 recheck of band pairs
__global__ void sim_recheck_k(const float* __restrict__ f1, const float* __restrict__ f2,
                              const float* __restrict__ invn,
                              const unsigned* __restrict__ cands, const int* __restrict__ ccount,
                              u64* __restrict__ msim, u64* __restrict__ mamb, int s) {
  int lane = threadIdx.x & 63;
  int gw = (blockIdx.x * blockDim.x + threadIdx.x) >> 6;
  int nw = (gridDim.x * blockDim.x) >> 6;
  int n = *ccount; if (n > CANDMAX) n = CANDMAX;
  for (int i = gw; i < n; i += nw) {
    unsigned pk = cands[i];
    int r = (int)(pk >> 15), c = (int)(pk & 0x7fffu);
    const float4* pa = (const float4*)(f1 + (size_t)r * Dc);
    const float4* pb = (const float4*)(f2 + ((size_t)s * SPLITc + c) * Dc);
    float4 a0 = pa[lane], a1 = pa[lane + 64];
    float4 b0 = pb[lane], b1 = pb[lane + 64];
    float d = a0.x*b0.x + a0.y*b0.y + a0.z*b0.z + a0.w*b0.w
            + a1.x*b1.x + a1.y*b1.y + a1.z*b1.z + a1.w*b1.w;
    #pragma unroll
    for (int t = 1; t < 64; t <<= 1) d += __shfl_xor(d, t);
    if (lane == 0) {
      float v = d * invn[r] * invn[N1c + s * SPLITc + c];
      if (v > SIM_Tc)
        atomicOr(&msim[(size_t)r * WPSc + (c >> 6)], 1ull << (c & 63));
      else if (v > AMB_Tc)
        atomicOr(&mamb[(size_t)r * WPSc + (c >> 6)], 1ull << (c & 63));
    }
  }
}

// ---------------------------------------------------------------- per-row counts
__global__ void sim_rowcount_k(const u64* __restrict__ msim, const u64* __restrict__ mamb,
                               int* __restrict__ rowcnt) {
  int row = blockIdx.x;
  int wid = threadIdx.x >> 6, lane = threadIdx.x & 63;
  const u64* m = wid ? mamb : msim;
  int ssum = 0;
  #pragma unroll
  for (int it = 0; it < WPSc / 64; ++it)
    ssum += __popcll(m[(size_t)row * WPSc + it * 64 + lane]);
  #pragma unroll
  for (int d = 32; d; d >>= 1) ssum += __shfl_down(ssum, d);
  if (lane == 0) rowcnt[wid * N1c + row] = ssum;
}

// ---------------------------------------------------------------- exclusive scan over 4096 rows
__global__ void sim_scan_k(const int* __restrict__ rowcnt, int* __restrict__ rowoff) {
  int cat = blockIdx.x;
  int tid = threadIdx.x;                  // 256 threads x 16 rows
  int v[16]; int ssum = 0;
  #pragma unroll
  for (int i = 0; i < 16; ++i) { v[i] = rowcnt[cat * N1c + tid * 16 + i]; ssum += v[i]; }
  int lane = tid & 63, wid = tid >> 6;
  int incl = ssum;
  #pragma unroll
  for (int d = 1; d < 64; d <<= 1) { int t = __shfl_up(incl, d); if (lane >= d) incl += t; }
  __shared__ int wsum[4];
  if (lane == 63) wsum[wid] = incl;
  __syncthreads();
  int woff = 0;
  for (int w = 0; w < wid; ++w) woff += wsum[w];
  int run = woff + incl - ssum;
  #pragma unroll
  for (int i = 0; i < 16; ++i) { rowoff[cat * N1c + tid * 16 + i] = run; run += v[i]; }
}

// ---------------------------------------------------------------- ordered scatter
__global__ void sim_scatter_k(const u64* __restrict__ msim, const u64* __restrict__ mamb,
                              const int* __restrict__ rowoff,
                              const int* __restrict__ labels, const int* __restrict__ counts,
                              const int* __restrict__ labels_db, const int* __restrict__ counts_db,
                              int* __restrict__ out, int s) {
  int row = blockIdx.x;
  int cat = blockIdx.y;
  int lane = threadIdx.x;
  const u64* m = cat ? mamb : msim;
  int* o = out + (cat ? (NSPLITc * CAPc * 2 + s * CAPc * 2) : (s * CAPc * 2));
  int run = rowoff[cat * N1c + row];
  int lab1 = labels[row];
  int cnt1 = counts[row];
  for (int it = 0; it < WPSc / 64; ++it) {
    int w = it * 64 + lane;
    u64 x = m[(size_t)row * WPSc + w];
    int pc = __popcll(x);
    int incl = pc;
    #pragma unroll
    for (int d = 1; d < 64; d <<= 1) { int t = __shfl_up(incl, d); if (lane >= d) incl += t; }
    int pos = run + incl - pc;
    int tot = __shfl(incl, 63);
    while (x) {
      int b = __builtin_ctzll(x);
      x &= x - 1;
      if (pos < CAPc) {
        int gc = s * SPLITc + w * 64 + b;
        int l2v = labels_db[gc];
        if (cat == 0) {
          o[2 * pos]     = lab1;
          o[2 * pos + 1] = l2v;
        } else {
          bool sw = cnt1 > counts_db[gc];
          o[2 * pos]     = sw ? l2v : lab1;
          o[2 * pos + 1] = sw ? lab1 : l2v;
        }
      }
      ++pos;
    }
    run += tot;
  }
}

// ---------------------------------------------------------------- launcher
extern "C" void kernel_launch(void* const* d_in, const int* in_sizes, int n_in,
                              void* d_out, int out_size, void* d_ws, size_t ws_size,
                              hipStream_t stream) {
  const float* features    = (const float*)d_in[0];
  const int*   labels      = (const int*)  d_in[1];
  const int*   counts      = (const int*)  d_in[2];
  const int*   indexes     = (const int*)  d_in[3];
  const float* features_db = (const float*)d_in[4];
  const int*   labels_db   = (const int*)  d_in[5];
  const int*   counts_db   = (const int*)  d_in[6];
  const int*   indexes_db  = (const int*)  d_in[7];
  int* out = (int*)d_out;

  // workspace layout (~57.5 MB)
  u64*   msim   = (u64*)d_ws;                           // 12.58 MB
  u64*   mamb   = msim + (size_t)N1c * WPSc;            // 12.58 MB
  float* invn   = (float*)(mamb + (size_t)N1c * WPSc);  // (N1+N2) f32
  int*   rowcnt = (int*)(invn + (N1c + N2c));           // [2][N1]
  int*   rowoff = rowcnt + 2 * N1c;                     // [2][N1]
  int*   ccount = rowoff + 2 * N1c;                     // [2] (+pad)
  unsigned* cands = (unsigned*)(ccount + 4);            // 4 MB
  unsigned short* f1nb = (unsigned short*)(cands + CANDMAX);  // 4 MB
  unsigned short* f2nb = f1nb + (size_t)N1c * Dc;       // 24 MB (per split, reused)

  sim_fill_out_k<<<(out_size + 255) / 256, 256, 0, stream>>>(out, out_size, ccount);
  sim_norm_k<<<(N1c + N2c + 3) / 4, 256, 0, stream>>>(features, features_db, invn, f1nb, f2nb);

  for (int s = 0; s < NSPLITc; ++s) {
    if (s) sim_conv2_k<<<SPLITc / 4, 256, 0, stream>>>(features_db, invn, f2nb, s);
    sim_mfma_k<<<dim3(SPLITc / 128, N1c / 128), 256, 0, stream>>>(
        f1nb, f2nb, labels, indexes, labels_db, indexes_db,
        msim, mamb, cands, ccount + s, s);
    sim_recheck_k<<<512, 256, 0, stream>>>(features, features_db, invn,
                                           cands, ccount + s, msim, mamb, s);
    sim_rowcount_k<<<N1c, 128, 0, stream>>>(msim, mamb, rowcnt);
    sim_scan_k<<<2, 256, 0, stream>>>(rowcnt, rowoff);
    sim_scatter_k<<<dim3(N1c, 2), 64, 0, stream>>>(
        msim, mamb, rowoff, labels, counts, labels_db, counts_db, out, s);
  }
}